// Round 19
// baseline (426.296 us; speedup 1.0000x reference)
//
#include <hip/hip_runtime.h>
#include <hip/hip_bf16.h>
#include <hip/hip_fp16.h>
#include <hip/hip_cooperative_groups.h>
#include <math.h>

namespace cg = cooperative_groups;

typedef _Float16 half8 __attribute__((ext_vector_type(8)));
typedef float f32x4 __attribute__((ext_vector_type(4)));

__device__ __forceinline__ float tanh_fast(float v) {
  // tanh(v) = 1 - 2/(exp(2v)+1); saturates correctly at +/-inf
  float e = __expf(v + v);
  return 1.0f - 2.0f * __builtin_amdgcn_rcpf(e + 1.0f);
}

__device__ __forceinline__ float dot8h(float4 a, float4 b) {
  const __half2* pa = (const __half2*)&a;
  const __half2* pb = (const __half2*)&b;
  float s = 0.0f;
#pragma unroll
  for (int i = 0; i < 4; ++i) {
    float2 fa = __half22float2(pa[i]);
    float2 fb = __half22float2(pb[i]);
    s = fmaf(fa.x, fb.x, s);
    s = fmaf(fa.y, fb.y, s);
  }
  return s;
}

// ---------------------------------------------------------------------------
// k_zero: workspace zeroing (memset-equivalent).
// ---------------------------------------------------------------------------
__global__ void k_zero(uint4* __restrict__ p, int n4) {
  int i = blockIdx.x * 256 + threadIdx.x;
  if (i < n4) p[i] = make_uint4(0u, 0u, 0u, 0u);
}

// ---------------------------------------------------------------------------
// Front kernel (r14 form, measured best): 2-tile pipelined MFMA GEMM,
// h = tanh(x@W^T+b) row-normalized -> fp16 scatter store. W register-staged
// in one burst into 32KB XOR-swizzled LDS. C mapping: col=l&15,
// row=(l>>4)*4+reg [m89/m91]. Fused tails: node inits + 8-way copy-split
// col histogram emitting ranks (copy=(e>>8)&7, block-uniform per pass ->
// cnt8 copy stays in one XCD L2). k_front sits at an unexplained ~46us
// floor (7 structural variants, 43-62us, all pipes idle) — accepted.
// ---------------------------------------------------------------------------
__global__ __launch_bounds__(256) void k_front(
    const float* __restrict__ x, const float* __restrict__ W,
    const float* __restrict__ bl, const float* __restrict__ mask,
    const int* __restrict__ cols, __half* __restrict__ hn,
    int* __restrict__ cnt8, unsigned short* __restrict__ rank,
    float* __restrict__ h0, float* __restrict__ f_a, int N, int E, int nblk,
    int wstride, int ntiles) {
  __shared__ _Float16 wsh[128 * 128];  // 32 KB, swizzled
  const int tid = threadIdx.x;
  const int bid = blockIdx.x;
  const int wv = tid >> 6, lane = tid & 63;
  const int r = lane & 15;  // A-row / B-col / C-col
  const int g = lane >> 4;  // k-group / C-row-group

  int t0 = bid * 4 + wv;  // first tile for this wave (< wstride <= ntiles)

  // ---- issue x loads for tile 0 immediately (independent of W stage) ----
  float4 xv[8];
  {
    const float4* xr = (const float4*)(x + (size_t)(t0 * 16 + r) * 128);
#pragma unroll
    for (int ks = 0; ks < 4; ++ks) {
      xv[ks * 2] = xr[ks * 8 + g * 2];
      xv[ks * 2 + 1] = xr[ks * 8 + g * 2 + 1];
    }
  }

  // ---- W stage, register-staged burst (16 loads in flight) ----
  {
    float4 wa[8], wb[8];
#pragma unroll
    for (int k = 0; k < 8; ++k) {
      int i = tid + k * 256;
      const float4* wr = (const float4*)(W + (i >> 4) * 128 + (i & 15) * 8);
      wa[k] = wr[0];
      wb[k] = wr[1];
    }
#pragma unroll
    for (int k = 0; k < 8; ++k) {
      int i = tid + k * 256;
      int row = i >> 4, cc = i & 15;
      half8 h;
      h[0] = (_Float16)wa[k].x; h[1] = (_Float16)wa[k].y;
      h[2] = (_Float16)wa[k].z; h[3] = (_Float16)wa[k].w;
      h[4] = (_Float16)wb[k].x; h[5] = (_Float16)wb[k].y;
      h[6] = (_Float16)wb[k].z; h[7] = (_Float16)wb[k].w;
      *(half8*)((char*)wsh + row * 256 + ((cc * 16) ^ ((row & 7) << 4))) = h;
    }
  }
  __syncthreads();

  // ---- bias per lane-column, hoisted across tiles ----
  float bv[8];
#pragma unroll
  for (int c = 0; c < 8; ++c) bv[c] = bl[c * 16 + r];

  // ---- 2-tile pipelined loop ----
  int t = t0;
#pragma unroll
  for (int it = 0; it < 2; ++it) {
    const int row0 = t * 16;
    half8 afrag[4];
#pragma unroll
    for (int ks = 0; ks < 4; ++ks) {
      float4 lo = xv[ks * 2], hi = xv[ks * 2 + 1];
      half8 a;
      a[0] = (_Float16)lo.x; a[1] = (_Float16)lo.y;
      a[2] = (_Float16)lo.z; a[3] = (_Float16)lo.w;
      a[4] = (_Float16)hi.x; a[5] = (_Float16)hi.y;
      a[6] = (_Float16)hi.z; a[7] = (_Float16)hi.w;
      afrag[ks] = a;
    }
    const int tn = t + wstride;
    const bool hasnext = (it == 0) && (tn < ntiles);
    if (hasnext) {
      const float4* xr = (const float4*)(x + (size_t)(tn * 16 + r) * 128);
#pragma unroll
      for (int ks = 0; ks < 4; ++ks) {
        xv[ks * 2] = xr[ks * 8 + g * 2];
        xv[ks * 2 + 1] = xr[ks * 8 + g * 2 + 1];
      }
    }
    f32x4 acc[8];
#pragma unroll
    for (int c = 0; c < 8; ++c) acc[c] = (f32x4){0.f, 0.f, 0.f, 0.f};
#pragma unroll
    for (int c = 0; c < 8; ++c) {
      const char* base = (const char*)wsh + (c * 16 + r) * 256;
      const int sw = ((c * 16 + r) & 7) << 4;
#pragma unroll
      for (int ks = 0; ks < 4; ++ks) {
        half8 b = *(const half8*)(base + ((ks * 64 + g * 16) ^ sw));
        acc[c] = __builtin_amdgcn_mfma_f32_16x16x32_f16(afrag[ks], b, acc[c],
                                                        0, 0, 0);
      }
    }
    float tt[8][4];
    float ss[4] = {0.f, 0.f, 0.f, 0.f};
#pragma unroll
    for (int c = 0; c < 8; ++c) {
#pragma unroll
      for (int j = 0; j < 4; ++j) {
        float tv = tanh_fast(acc[c][j] + bv[c]);
        tt[c][j] = tv;
        ss[j] = fmaf(tv, tv, ss[j]);
      }
    }
#pragma unroll
    for (int j = 0; j < 4; ++j) {
#pragma unroll
      for (int o = 8; o; o >>= 1) ss[j] += __shfl_xor(ss[j], o);
      ss[j] = 1.0f / fmaxf(sqrtf(ss[j]), 1e-8f);
    }
#pragma unroll
    for (int c = 0; c < 8; ++c)
#pragma unroll
      for (int j = 0; j < 4; ++j)
        hn[(size_t)(row0 + g * 4 + j) * 128 + c * 16 + r] =
            __float2half_rn(tt[c][j] * ss[j]);
    if (!hasnext) break;
    t = tn;
  }

  // ---- grid-stride tails: node inits + copy-split histogram with ranks ----
  const int tg = bid * 256 + tid;
  const int NT = nblk * 256;
  for (int i = tg; i < N; i += NT) {
    float v = fmaxf(mask[i], 0.0f);
    h0[i] = v;
    f_a[i] = v;
  }
  for (int e = tg; e < E; e += NT) {
    int c = cols[e];
    int copy = (e >> 8) & 7;  // block-uniform per pass ~ XCD id
    int rk = atomicAdd(cnt8 + copy * N + c, 1);
    rank[e] = (unsigned short)rk;
  }
}

// ---------------------------------------------------------------------------
// Scan step 1: per-256-chunk block sums of tot[c] = sum_j cnt8[j][c].
// ---------------------------------------------------------------------------
__global__ __launch_bounds__(256) void k_scan_a(const int* __restrict__ cnt8,
                                                int* __restrict__ bsum,
                                                int N) {
  __shared__ int s[256];
  int i = blockIdx.x * 256 + threadIdx.x;
  int tot = 0;
  if (i < N) {
#pragma unroll
    for (int j = 0; j < 8; ++j) tot += cnt8[j * N + i];
  }
  s[threadIdx.x] = tot;
  __syncthreads();
  for (int d = 128; d; d >>= 1) {
    if (threadIdx.x < d) s[threadIdx.x] += s[threadIdx.x + d];
    __syncthreads();
  }
  if (threadIdx.x == 0) bsum[blockIdx.x] = s[0];
}

// ---------------------------------------------------------------------------
// Scan step 2: each block redundantly scans the <=256 block sums in LDS, then
// scans its own 256-chunk of tot -> off[c]; converts cnt8 in place to the
// per-copy bases: cnt8[j][c] := off[c] + sum_{i<j} cnt8[i][c].
// ---------------------------------------------------------------------------
__global__ __launch_bounds__(256) void k_scan_bc(int* __restrict__ cnt8,
                                                 const int* __restrict__ bsum,
                                                 int* __restrict__ off, int N,
                                                 int E, int NCH) {
  __shared__ int bscan[2 * 256];
  __shared__ int cscan[2 * 256];
  const int t = threadIdx.x, bid = blockIdx.x;
  int bv = (t < NCH) ? bsum[t] : 0;
  bscan[t] = bv;
  __syncthreads();
  int a = 0;
  for (int d = 1; d < 256; d <<= 1) {
    int v2 = bscan[a * 256 + t];
    if (t >= d) v2 += bscan[a * 256 + t - d];
    bscan[(a ^ 1) * 256 + t] = v2;
    __syncthreads();
    a ^= 1;
  }
  int bpre = (bid > 0) ? bscan[a * 256 + bid - 1] : 0;  // exclusive prefix
  int i = bid * 256 + t;
  int cj[8];
  int tot = 0;
  if (i < N) {
#pragma unroll
    for (int j = 0; j < 8; ++j) {
      cj[j] = cnt8[j * N + i];
      tot += cj[j];
    }
  }
  cscan[t] = tot;
  __syncthreads();
  int b2 = 0;
  for (int d = 1; d < 256; d <<= 1) {
    int v2 = cscan[b2 * 256 + t];
    if (t >= d) v2 += cscan[b2 * 256 + t - d];
    cscan[(b2 ^ 1) * 256 + t] = v2;
    __syncthreads();
    b2 ^= 1;
  }
  if (i < N) {
    int excl = cscan[b2 * 256 + t] - tot + bpre;
    off[i] = excl;
    int run = excl;
#pragma unroll
    for (int j = 0; j < 8; ++j) {
      cnt8[j * N + i] = run;  // base for copy j
      run += cj[j];
    }
  }
  if (bid == 0 && t == 0) off[N] = E;
}

// ---------------------------------------------------------------------------
// Build, atomic-free: pos = base8[copy][c] + rank[e]. Unique by construction.
// ---------------------------------------------------------------------------
__global__ void k_build(const int* __restrict__ rows,
                        const int* __restrict__ cols,
                        const int* __restrict__ base8,
                        const unsigned short* __restrict__ rank,
                        unsigned* __restrict__ rec, int* __restrict__ perm,
                        int N, int E) {
  int e = blockIdx.x * 256 + threadIdx.x;
  if (e >= E) return;
  unsigned r = (unsigned)rows[e], c = (unsigned)cols[e];
  int copy = (e >> 8) & 7;
  int pos = base8[copy * N + (int)c] + (int)rank[e];
  rec[pos] = r | (c << 16);
  perm[e] = pos;
}

// ---------------------------------------------------------------------------
// Edge cosine, col-sorted, 4 lanes/edge x 2 edges per quad (p and p+Q).
// All 8 random row-loads issued first; col loads (L1/L2-hot) follow.
// Sequential writes only.
// ---------------------------------------------------------------------------
__global__ __launch_bounds__(256) void k_edge_cos(
    const __half* __restrict__ hn, const unsigned* __restrict__ rec,
    float* __restrict__ csr_w, unsigned short* __restrict__ src16, int E,
    int Q) {
  int t = blockIdx.x * 256 + threadIdx.x;
  int q = t >> 2, sub = t & 3;
  if (q >= Q) return;
  const int p0 = q, p1 = q + Q;
  const bool has1 = p1 < E;
  unsigned rc0 = rec[p0];
  unsigned rc1 = has1 ? rec[p1] : rc0;
  const float4* hr0 = (const float4*)(hn + (size_t)(rc0 & 0xffffu) * 128);
  const float4* hr1 = (const float4*)(hn + (size_t)(rc1 & 0xffffu) * 128);
  float4 r00 = hr0[sub], r01 = hr0[sub + 4], r02 = hr0[sub + 8],
         r03 = hr0[sub + 12];
  float4 r10 = hr1[sub], r11 = hr1[sub + 4], r12 = hr1[sub + 8],
         r13 = hr1[sub + 12];
  const float4* hc0 = (const float4*)(hn + (size_t)(rc0 >> 16) * 128);
  const float4* hc1 = (const float4*)(hn + (size_t)(rc1 >> 16) * 128);
  float d0 = dot8h(r00, hc0[sub]) + dot8h(r01, hc0[sub + 4]) +
             dot8h(r02, hc0[sub + 8]) + dot8h(r03, hc0[sub + 12]);
  float d1 = dot8h(r10, hc1[sub]) + dot8h(r11, hc1[sub + 4]) +
             dot8h(r12, hc1[sub + 8]) + dot8h(r13, hc1[sub + 12]);
  d0 += __shfl_xor(d0, 1);
  d0 += __shfl_xor(d0, 2);
  d1 += __shfl_xor(d1, 1);
  d1 += __shfl_xor(d1, 2);
  if (sub == 0) {
    csr_w[p0] = fmaxf(d0, 0.0f);
    src16[p0] = (unsigned short)(rc0 & 0xffffu);
    if (has1) {
      csr_w[p1] = fmaxf(d1, 0.0f);
      src16[p1] = (unsigned short)(rc1 & 0xffffu);
    }
  }
}

// ---------------------------------------------------------------------------
// Fused: un-permute raw weights to ew[e] + segmented degree sum -> rsd.
// ---------------------------------------------------------------------------
__global__ __launch_bounds__(256) void k_unperm_rsd(
    const float* __restrict__ csr_w, const int* __restrict__ perm,
    const int* __restrict__ off, float* __restrict__ ew,
    float* __restrict__ rsd, int N, int E) {
  int t = blockIdx.x * 256 + threadIdx.x;
  if (t < E) ew[t] = csr_w[perm[t]];
  int n = t >> 2, sub = t & 3;
  if (n < N) {
    int s0 = off[n], s1 = off[n + 1];
    float s = 0.0f;
    for (int i = s0 + sub; i < s1; i += 4) s += csr_w[i];
    s += __shfl_xor(s, 1);
    s += __shfl_xor(s, 2);
    if (sub == 0) rsd[n] = rsqrtf(1.0f + s);  // self-loop weight 1
  }
}

// ---------------------------------------------------------------------------
// ALL 5 APPNP iterations in ONE cooperative kernel (grid.sync between
// iterations replaces 4 dispatch boundaries). Per-quad invariants hoisted
// once: rs^2, h0, segment bounds, alpha; first 4 edges per lane cached in
// STATICALLY-indexed registers (rule #20) with zero-weight padding; spill
// edges (>16/node) read from L2-hot csr_w/src16 each iteration.
// csr_w normalized in the hoist phase (same math as old mode-0 pass).
// ---------------------------------------------------------------------------
__global__ __launch_bounds__(256) void k_prop_all(
    float* __restrict__ f_a, float* __restrict__ f_b,
    float* __restrict__ csr_w, const unsigned short* __restrict__ src16,
    const int* __restrict__ off, const float* __restrict__ h0,
    const float* __restrict__ rsd, const float* __restrict__ alpha_p,
    const float* __restrict__ bias_p, float* __restrict__ fill, int N) {
  cg::grid_group grid = cg::this_grid();
  const int t = blockIdx.x * 256 + threadIdx.x;
  const int n = t >> 2, sub = t & 3;
  const bool active = n < N;
  const float a = alpha_p[0];

  float rs_n = 0.f, selfw = 0.f, h0v = 0.f;
  int s0 = 0, s1 = 0, ispill = 0;
  float w0 = 0.f, w1 = 0.f, w2 = 0.f, w3 = 0.f;
  int sx0 = 0, sx1 = 0, sx2 = 0, sx3 = 0;

  if (active) {
    rs_n = rsd[n];
    selfw = rs_n * rs_n;
    h0v = h0[n];
    s0 = off[n];
    s1 = off[n + 1];
    // normalize whole segment in place (once)
    for (int i = s0 + sub; i < s1; i += 4) {
      int s = src16[i];
      csr_w[i] *= rs_n * rsd[s];
    }
    // cache first 4 owned edges in static registers (pad with weight 0)
    const int i0 = s0 + sub;
    if (i0 < s1)          { sx0 = src16[i0];      w0 = csr_w[i0]; }
    if (i0 + 4 < s1)      { sx1 = src16[i0 + 4];  w1 = csr_w[i0 + 4]; }
    if (i0 + 8 < s1)      { sx2 = src16[i0 + 8];  w2 = csr_w[i0 + 8]; }
    if (i0 + 12 < s1)     { sx3 = src16[i0 + 12]; w3 = csr_w[i0 + 12]; }
    ispill = i0 + 16;
  }

  const float bvl = bias_p[0];
  const float sp = (bvl > 20.0f) ? bvl : log1pf(expf(bvl));

#pragma unroll
  for (int it = 0; it < 5; ++it) {
    const float* fi = (it & 1) ? f_b : f_a;
    float* fo = (it & 1) ? f_a : f_b;
    if (active) {
      float part = w0 * fi[sx0];  // padded edges: w==0 -> contributes 0
      part = fmaf(w1, fi[sx1], part);
      part = fmaf(w2, fi[sx2], part);
      part = fmaf(w3, fi[sx3], part);
      for (int i = ispill; i < s1; i += 4)
        part = fmaf(csr_w[i], fi[src16[i]], part);
      part += __shfl_xor(part, 1);
      part += __shfl_xor(part, 2);
      if (sub == 0) {
        float agg = part + fi[n] * selfw;  // self-loop: norm = 1/deg
        float fn = (1.0f - a) * agg + a * h0v;
        if (it == 4)
          fill[n] = tanhf(fn - sp);
        else
          fo[n] = fn;
      }
    }
    if (it < 4) grid.sync();
  }
}

// ---------------------------------------------------------------------------
extern "C" void kernel_launch(void* const* d_in, const int* in_sizes, int n_in,
                              void* d_out, int out_size, void* d_ws,
                              size_t ws_size, hipStream_t stream) {
  const float* x = (const float*)d_in[0];
  const float* mask = (const float*)d_in[1];
  const int* ei = (const int*)d_in[2];  // [2, E] int32 (jax x64 disabled)
  const float* W = (const float*)d_in[3];
  const float* bl = (const float*)d_in[4];
  const float* alpha = (const float*)d_in[5];
  const float* bias = (const float*)d_in[6];

  const int D = 128;
  const int N = in_sizes[0] / D;  // 50000  (< 65536: u16 node ids)
  const int E = in_sizes[2] / 2;  // 600000
  const int* rows = ei;
  const int* cols = ei + E;

  float* fill = (float*)d_out;    // [N]
  float* ew = (float*)d_out + N;  // [E] edge_weights output slice

  // workspace carve-up (256B aligned)
  char* w = (char*)d_ws;
  size_t off_b = 0;
  auto alloc = [&](size_t bytes) -> void* {
    void* p = (void*)(w + off_b);
    off_b = (off_b + bytes + 255) & ~(size_t)255;
    return p;
  };
  __half* hn = (__half*)alloc((size_t)N * D * sizeof(__half));  // 12.8 MB
  int* cnt8 = (int*)alloc((size_t)8 * N * sizeof(int));         // 1.6 MB
  unsigned short* rank =
      (unsigned short*)alloc((size_t)E * sizeof(unsigned short));  // 1.2 MB
  int* off = (int*)alloc((size_t)(N + 1) * sizeof(int));
  int* bsum = (int*)alloc(256 * sizeof(int));
  unsigned* rec = (unsigned*)alloc((size_t)E * sizeof(unsigned));  // 2.4 MB
  int* perm = (int*)alloc((size_t)E * sizeof(int));                // 2.4 MB
  float* csr_w = (float*)alloc((size_t)E * sizeof(float));         // 2.4 MB
  unsigned short* src16 =
      (unsigned short*)alloc((size_t)E * sizeof(unsigned short));
  float* h0 = (float*)alloc((size_t)N * sizeof(float));
  float* f_a = (float*)alloc((size_t)N * sizeof(float));
  float* f_b = (float*)alloc((size_t)N * sizeof(float));
  float* rsd = (float*)alloc((size_t)N * sizeof(float));
  (void)ws_size;

  const int NCH = (N + 255) / 256;  // 196 <= 256 (scan capacity)
  const int nb_E = (E + 255) / 256;
  const int NTILES = (N + 15) / 16;           // 3125 16-row tiles
  const int FRONT_BLOCKS = (NTILES + 7) / 8;  // 391: 4 waves x 2 tiles
  const int WSTRIDE = FRONT_BLOCKS * 4;       // 1564

  // zero cnt8 (own kernel; memset-equivalent)
  const int n4 = (8 * N + 3) / 4;  // 100000 uint4
  k_zero<<<(n4 + 255) / 256, 256, 0, stream>>>((uint4*)cnt8, n4);
  // 2-tile pipelined GEMM + inits + copy-split histogram/rank
  k_front<<<FRONT_BLOCKS, 256, 0, stream>>>(x, W, bl, mask, cols, hn, cnt8,
                                            rank, h0, f_a, N, E, FRONT_BLOCKS,
                                            WSTRIDE, NTILES);
  // exclusive scan of totals -> off; cnt8 -> per-copy bases (in place)
  k_scan_a<<<NCH, 256, 0, stream>>>(cnt8, bsum, N);
  k_scan_bc<<<NCH, 256, 0, stream>>>(cnt8, bsum, off, N, E, NCH);
  // atomic-free col-sorted records + inverse permutation
  k_build<<<nb_E, 256, 0, stream>>>(rows, cols, cnt8, rank, rec, perm, N, E);
  // cosine in sorted order -> csr_w + src16 (2 edges per lane-quad)
  const int Q = (E + 1) / 2;
  k_edge_cos<<<(Q * 4 + 255) / 256, 256, 0, stream>>>(hn, rec, csr_w, src16,
                                                      E, Q);
  // un-permute raw weights to ew (d_out) + segmented degree -> rsd
  k_unperm_rsd<<<nb_E, 256, 0, stream>>>(csr_w, perm, off, ew, rsd, N, E);
  // K=5 APPNP iterations in ONE cooperative dispatch (grid.sync inside)
  {
    const int PROP_BLOCKS = (N * 4 + 255) / 256;  // 782 <= co-residency cap
    float* f_a_p = f_a;
    float* f_b_p = f_b;
    float* csr_w_p = csr_w;
    const unsigned short* src16_p = src16;
    const int* off_p = off;
    const float* h0_p = h0;
    const float* rsd_p = rsd;
    const float* alpha_p = alpha;
    const float* bias_p = bias;
    float* fill_p = fill;
    int N_v = N;
    void* args[] = {&f_a_p, &f_b_p, &csr_w_p, &src16_p, &off_p, &h0_p,
                    &rsd_p, &alpha_p, &bias_p, &fill_p, &N_v};
    hipLaunchCooperativeKernel((const void*)k_prop_all, dim3(PROP_BLOCKS),
                               dim3(256), args, 0, stream);
  }
}

// Round 20
// 117.871 us; speedup vs baseline: 3.6166x; 3.6166x over previous
//
#include <hip/hip_runtime.h>
#include <hip/hip_bf16.h>
#include <hip/hip_fp16.h>
#include <math.h>

typedef _Float16 half8 __attribute__((ext_vector_type(8)));
typedef float f32x4 __attribute__((ext_vector_type(4)));

__device__ __forceinline__ float tanh_fast(float v) {
  // tanh(v) = 1 - 2/(exp(2v)+1); saturates correctly at +/-inf
  float e = __expf(v + v);
  return 1.0f - 2.0f * __builtin_amdgcn_rcpf(e + 1.0f);
}

__device__ __forceinline__ float dot8h(float4 a, float4 b) {
  const __half2* pa = (const __half2*)&a;
  const __half2* pb = (const __half2*)&b;
  float s = 0.0f;
#pragma unroll
  for (int i = 0; i < 4; ++i) {
    float2 fa = __half22float2(pa[i]);
    float2 fb = __half22float2(pb[i]);
    s = fmaf(fa.x, fb.x, s);
    s = fmaf(fa.y, fb.y, s);
  }
  return s;
}

// ---------------------------------------------------------------------------
// k_zero: workspace zeroing (memset-equivalent). Now only 800KB (packed).
// ---------------------------------------------------------------------------
__global__ void k_zero(uint4* __restrict__ p, int n4) {
  int i = blockIdx.x * 256 + threadIdx.x;
  if (i < n4) p[i] = make_uint4(0u, 0u, 0u, 0u);
}

// ---------------------------------------------------------------------------
// Front kernel (r14 form + PACKED counters): 2-tile pipelined MFMA GEMM,
// h = tanh(x@W^T+b) row-normalized -> fp16. W register-staged in one burst
// into 32KB XOR-swizzled LDS. C mapping: col=l&15, row=(l>>4)*4+reg [m89/91].
// Fused tails: node inits + 8-way copy-split col histogram with PACKED
// u32 counters (two adjacent cols share a word, 16-bit halves; max col
// degree ~40 << 65535). cntp = u32[8][W], W=N/2: 800KB total, 100KB per
// XCD copy — halves the atomic-line thrash that dominated k_front's
// 18MB excess WRITE traffic. copy=(e>>8)&7 block-uniform per pass.
// ---------------------------------------------------------------------------
__global__ __launch_bounds__(256) void k_front(
    const float* __restrict__ x, const float* __restrict__ W,
    const float* __restrict__ bl, const float* __restrict__ mask,
    const int* __restrict__ cols, __half* __restrict__ hn,
    unsigned* __restrict__ cntp, unsigned short* __restrict__ rank,
    float* __restrict__ h0, float* __restrict__ f_a, int N, int E, int nblk,
    int wstride, int ntiles, int Wn) {
  __shared__ _Float16 wsh[128 * 128];  // 32 KB, swizzled
  const int tid = threadIdx.x;
  const int bid = blockIdx.x;
  const int wv = tid >> 6, lane = tid & 63;
  const int r = lane & 15;  // A-row / B-col / C-col
  const int g = lane >> 4;  // k-group / C-row-group

  int t0 = bid * 4 + wv;  // first tile for this wave (< wstride <= ntiles)

  // ---- issue x loads for tile 0 immediately (independent of W stage) ----
  float4 xv[8];
  {
    const float4* xr = (const float4*)(x + (size_t)(t0 * 16 + r) * 128);
#pragma unroll
    for (int ks = 0; ks < 4; ++ks) {
      xv[ks * 2] = xr[ks * 8 + g * 2];
      xv[ks * 2 + 1] = xr[ks * 8 + g * 2 + 1];
    }
  }

  // ---- W stage, register-staged burst (16 loads in flight) ----
  {
    float4 wa[8], wb[8];
#pragma unroll
    for (int k = 0; k < 8; ++k) {
      int i = tid + k * 256;
      const float4* wr = (const float4*)(W + (i >> 4) * 128 + (i & 15) * 8);
      wa[k] = wr[0];
      wb[k] = wr[1];
    }
#pragma unroll
    for (int k = 0; k < 8; ++k) {
      int i = tid + k * 256;
      int row = i >> 4, cc = i & 15;
      half8 h;
      h[0] = (_Float16)wa[k].x; h[1] = (_Float16)wa[k].y;
      h[2] = (_Float16)wa[k].z; h[3] = (_Float16)wa[k].w;
      h[4] = (_Float16)wb[k].x; h[5] = (_Float16)wb[k].y;
      h[6] = (_Float16)wb[k].z; h[7] = (_Float16)wb[k].w;
      *(half8*)((char*)wsh + row * 256 + ((cc * 16) ^ ((row & 7) << 4))) = h;
    }
  }
  __syncthreads();

  // ---- bias per lane-column, hoisted across tiles ----
  float bv[8];
#pragma unroll
  for (int c = 0; c < 8; ++c) bv[c] = bl[c * 16 + r];

  // ---- 2-tile pipelined loop ----
  int t = t0;
#pragma unroll
  for (int it = 0; it < 2; ++it) {
    const int row0 = t * 16;
    half8 afrag[4];
#pragma unroll
    for (int ks = 0; ks < 4; ++ks) {
      float4 lo = xv[ks * 2], hi = xv[ks * 2 + 1];
      half8 a;
      a[0] = (_Float16)lo.x; a[1] = (_Float16)lo.y;
      a[2] = (_Float16)lo.z; a[3] = (_Float16)lo.w;
      a[4] = (_Float16)hi.x; a[5] = (_Float16)hi.y;
      a[6] = (_Float16)hi.z; a[7] = (_Float16)hi.w;
      afrag[ks] = a;
    }
    const int tn = t + wstride;
    const bool hasnext = (it == 0) && (tn < ntiles);
    if (hasnext) {
      const float4* xr = (const float4*)(x + (size_t)(tn * 16 + r) * 128);
#pragma unroll
      for (int ks = 0; ks < 4; ++ks) {
        xv[ks * 2] = xr[ks * 8 + g * 2];
        xv[ks * 2 + 1] = xr[ks * 8 + g * 2 + 1];
      }
    }
    f32x4 acc[8];
#pragma unroll
    for (int c = 0; c < 8; ++c) acc[c] = (f32x4){0.f, 0.f, 0.f, 0.f};
#pragma unroll
    for (int c = 0; c < 8; ++c) {
      const char* base = (const char*)wsh + (c * 16 + r) * 256;
      const int sw = ((c * 16 + r) & 7) << 4;
#pragma unroll
      for (int ks = 0; ks < 4; ++ks) {
        half8 b = *(const half8*)(base + ((ks * 64 + g * 16) ^ sw));
        acc[c] = __builtin_amdgcn_mfma_f32_16x16x32_f16(afrag[ks], b, acc[c],
                                                        0, 0, 0);
      }
    }
    float tt[8][4];
    float ss[4] = {0.f, 0.f, 0.f, 0.f};
#pragma unroll
    for (int c = 0; c < 8; ++c) {
#pragma unroll
      for (int j = 0; j < 4; ++j) {
        float tv = tanh_fast(acc[c][j] + bv[c]);
        tt[c][j] = tv;
        ss[j] = fmaf(tv, tv, ss[j]);
      }
    }
#pragma unroll
    for (int j = 0; j < 4; ++j) {
#pragma unroll
      for (int o = 8; o; o >>= 1) ss[j] += __shfl_xor(ss[j], o);
      ss[j] = 1.0f / fmaxf(sqrtf(ss[j]), 1e-8f);
    }
#pragma unroll
    for (int c = 0; c < 8; ++c)
#pragma unroll
      for (int j = 0; j < 4; ++j)
        hn[(size_t)(row0 + g * 4 + j) * 128 + c * 16 + r] =
            __float2half_rn(tt[c][j] * ss[j]);
    if (!hasnext) break;
    t = tn;
  }

  // ---- grid-stride tails: node inits + packed copy-split histogram ----
  const int tg = bid * 256 + tid;
  const int NT = nblk * 256;
  for (int i = tg; i < N; i += NT) {
    float v = fmaxf(mask[i], 0.0f);
    h0[i] = v;
    f_a[i] = v;
  }
  for (int e = tg; e < E; e += NT) {
    int c = cols[e];
    int copy = (e >> 8) & 7;  // block-uniform per pass ~ XCD id
    int word = c >> 1, sh = (c & 1) << 4;
    unsigned rk = atomicAdd(cntp + (size_t)copy * Wn + word, 1u << sh);
    rank[e] = (unsigned short)((rk >> sh) & 0xffffu);
  }
}

// ---------------------------------------------------------------------------
// Scan step 1: per-256-chunk block sums of tot[c] = sum_j halfword(cntp).
// ---------------------------------------------------------------------------
__global__ __launch_bounds__(256) void k_scan_a(
    const unsigned* __restrict__ cntp, int* __restrict__ bsum, int N, int Wn) {
  __shared__ int s[256];
  int i = blockIdx.x * 256 + threadIdx.x;
  int tot = 0;
  if (i < N) {
    int word = i >> 1, sh = (i & 1) << 4;
#pragma unroll
    for (int j = 0; j < 8; ++j)
      tot += (int)((cntp[(size_t)j * Wn + word] >> sh) & 0xffffu);
  }
  s[threadIdx.x] = tot;
  __syncthreads();
  for (int d = 128; d; d >>= 1) {
    if (threadIdx.x < d) s[threadIdx.x] += s[threadIdx.x + d];
    __syncthreads();
  }
  if (threadIdx.x == 0) bsum[blockIdx.x] = s[0];
}

// ---------------------------------------------------------------------------
// Scan step 2: each block redundantly scans the <=256 block sums in LDS, then
// scans its own 256-chunk of tot -> off[c]; writes UNPACKED per-copy bases:
// base8[j][c] = off[c] + sum_{i<j} cnt[i][c].
// ---------------------------------------------------------------------------
__global__ __launch_bounds__(256) void k_scan_bc(
    const unsigned* __restrict__ cntp, const int* __restrict__ bsum,
    int* __restrict__ off, int* __restrict__ base8, int N, int E, int NCH,
    int Wn) {
  __shared__ int bscan[2 * 256];
  __shared__ int cscan[2 * 256];
  const int t = threadIdx.x, bid = blockIdx.x;
  int bv = (t < NCH) ? bsum[t] : 0;
  bscan[t] = bv;
  __syncthreads();
  int a = 0;
  for (int d = 1; d < 256; d <<= 1) {
    int v2 = bscan[a * 256 + t];
    if (t >= d) v2 += bscan[a * 256 + t - d];
    bscan[(a ^ 1) * 256 + t] = v2;
    __syncthreads();
    a ^= 1;
  }
  int bpre = (bid > 0) ? bscan[a * 256 + bid - 1] : 0;  // exclusive prefix
  int i = bid * 256 + t;
  int cj[8];
  int tot = 0;
  if (i < N) {
    int word = i >> 1, sh = (i & 1) << 4;
#pragma unroll
    for (int j = 0; j < 8; ++j) {
      cj[j] = (int)((cntp[(size_t)j * Wn + word] >> sh) & 0xffffu);
      tot += cj[j];
    }
  }
  cscan[t] = tot;
  __syncthreads();
  int b2 = 0;
  for (int d = 1; d < 256; d <<= 1) {
    int v2 = cscan[b2 * 256 + t];
    if (t >= d) v2 += cscan[b2 * 256 + t - d];
    cscan[(b2 ^ 1) * 256 + t] = v2;
    __syncthreads();
    b2 ^= 1;
  }
  if (i < N) {
    int excl = cscan[b2 * 256 + t] - tot + bpre;
    off[i] = excl;
    int run = excl;
#pragma unroll
    for (int j = 0; j < 8; ++j) {
      base8[j * N + i] = run;  // base for copy j
      run += cj[j];
    }
  }
  if (bid == 0 && t == 0) off[N] = E;
}

// ---------------------------------------------------------------------------
// Build, atomic-free: pos = base8[copy][c] + rank[e]. Unique by construction.
// ---------------------------------------------------------------------------
__global__ void k_build(const int* __restrict__ rows,
                        const int* __restrict__ cols,
                        const int* __restrict__ base8,
                        const unsigned short* __restrict__ rank,
                        unsigned* __restrict__ rec, int* __restrict__ perm,
                        int N, int E) {
  int e = blockIdx.x * 256 + threadIdx.x;
  if (e >= E) return;
  unsigned r = (unsigned)rows[e], c = (unsigned)cols[e];
  int copy = (e >> 8) & 7;
  int pos = base8[copy * N + (int)c] + (int)rank[e];
  rec[pos] = r | (c << 16);
  perm[e] = pos;
}

// ---------------------------------------------------------------------------
// Edge cosine, col-sorted, 4 lanes/edge x 2 edges per quad (p and p+Q).
// All 8 random row-loads issued first; col loads (L1/L2-hot) follow.
// Sequential writes only.
// ---------------------------------------------------------------------------
__global__ __launch_bounds__(256) void k_edge_cos(
    const __half* __restrict__ hn, const unsigned* __restrict__ rec,
    float* __restrict__ csr_w, unsigned short* __restrict__ src16, int E,
    int Q) {
  int t = blockIdx.x * 256 + threadIdx.x;
  int q = t >> 2, sub = t & 3;
  if (q >= Q) return;
  const int p0 = q, p1 = q + Q;
  const bool has1 = p1 < E;
  unsigned rc0 = rec[p0];
  unsigned rc1 = has1 ? rec[p1] : rc0;
  const float4* hr0 = (const float4*)(hn + (size_t)(rc0 & 0xffffu) * 128);
  const float4* hr1 = (const float4*)(hn + (size_t)(rc1 & 0xffffu) * 128);
  float4 r00 = hr0[sub], r01 = hr0[sub + 4], r02 = hr0[sub + 8],
         r03 = hr0[sub + 12];
  float4 r10 = hr1[sub], r11 = hr1[sub + 4], r12 = hr1[sub + 8],
         r13 = hr1[sub + 12];
  const float4* hc0 = (const float4*)(hn + (size_t)(rc0 >> 16) * 128);
  const float4* hc1 = (const float4*)(hn + (size_t)(rc1 >> 16) * 128);
  float d0 = dot8h(r00, hc0[sub]) + dot8h(r01, hc0[sub + 4]) +
             dot8h(r02, hc0[sub + 8]) + dot8h(r03, hc0[sub + 12]);
  float d1 = dot8h(r10, hc1[sub]) + dot8h(r11, hc1[sub + 4]) +
             dot8h(r12, hc1[sub + 8]) + dot8h(r13, hc1[sub + 12]);
  d0 += __shfl_xor(d0, 1);
  d0 += __shfl_xor(d0, 2);
  d1 += __shfl_xor(d1, 1);
  d1 += __shfl_xor(d1, 2);
  if (sub == 0) {
    csr_w[p0] = fmaxf(d0, 0.0f);
    src16[p0] = (unsigned short)(rc0 & 0xffffu);
    if (has1) {
      csr_w[p1] = fmaxf(d1, 0.0f);
      src16[p1] = (unsigned short)(rc1 & 0xffffu);
    }
  }
}

// ---------------------------------------------------------------------------
// Fused: un-permute raw weights to ew[e] + segmented degree sum -> rsd.
// ---------------------------------------------------------------------------
__global__ __launch_bounds__(256) void k_unperm_rsd(
    const float* __restrict__ csr_w, const int* __restrict__ perm,
    const int* __restrict__ off, float* __restrict__ ew,
    float* __restrict__ rsd, int N, int E) {
  int t = blockIdx.x * 256 + threadIdx.x;
  if (t < E) ew[t] = csr_w[perm[t]];
  int n = t >> 2, sub = t & 3;
  if (n < N) {
    int s0 = off[n], s1 = off[n + 1];
    float s = 0.0f;
    for (int i = s0 + sub; i < s1; i += 4) s += csr_w[i];
    s += __shfl_xor(s, 1);
    s += __shfl_xor(s, 2);
    if (sub == 0) rsd[n] = rsqrtf(1.0f + s);  // self-loop weight 1
  }
}

// ---------------------------------------------------------------------------
// One APPNP iteration, fused gather-reduce + update. 4 lanes per node.
// mode bit0: first iter, normalize csr_w in place (wn = raw*rsd[src]*rsd[n]).
// mode bit1: last iter, write fill = tanh(f - softplus(bias)) to d_out.
// ---------------------------------------------------------------------------
__global__ __launch_bounds__(256) void k_prop(
    const float* __restrict__ f_in, float* __restrict__ f_out,
    float* __restrict__ csr_w, const unsigned short* __restrict__ src16,
    const int* __restrict__ off, const float* __restrict__ h0,
    const float* __restrict__ rsd, const float* __restrict__ alpha_p,
    const float* __restrict__ bias_p, float* __restrict__ fill, int N,
    int mode) {
  int t = blockIdx.x * 256 + threadIdx.x;
  int n = t >> 2, sub = t & 3;
  if (n >= N) return;
  float rs_n = rsd[n];
  int s0 = off[n], s1 = off[n + 1];
  float part = 0.0f;
  if (mode & 1) {
    for (int i = s0 + sub; i < s1; i += 4) {
      int s = src16[i];
      float wn = csr_w[i] * rs_n * rsd[s];
      csr_w[i] = wn;  // segment owned by this node's 4 lanes; i unique
      part = fmaf(wn, f_in[s], part);
    }
  } else {
    for (int i = s0 + sub; i < s1; i += 4)
      part = fmaf(csr_w[i], f_in[src16[i]], part);
  }
  part += __shfl_xor(part, 1);
  part += __shfl_xor(part, 2);
  if (sub == 0) {
    float a = alpha_p[0];
    float agg = part + f_in[n] * rs_n * rs_n;  // self-loop: norm = 1/deg
    float fn = (1.0f - a) * agg + a * h0[n];
    if (mode & 2) {
      float b = bias_p[0];
      float sp = (b > 20.0f) ? b : log1pf(expf(b));
      fill[n] = tanhf(fn - sp);
    } else {
      f_out[n] = fn;
    }
  }
}

// ---------------------------------------------------------------------------
extern "C" void kernel_launch(void* const* d_in, const int* in_sizes, int n_in,
                              void* d_out, int out_size, void* d_ws,
                              size_t ws_size, hipStream_t stream) {
  const float* x = (const float*)d_in[0];
  const float* mask = (const float*)d_in[1];
  const int* ei = (const int*)d_in[2];  // [2, E] int32 (jax x64 disabled)
  const float* W = (const float*)d_in[3];
  const float* bl = (const float*)d_in[4];
  const float* alpha = (const float*)d_in[5];
  const float* bias = (const float*)d_in[6];

  const int D = 128;
  const int N = in_sizes[0] / D;  // 50000  (< 65536: u16 node ids)
  const int E = in_sizes[2] / 2;  // 600000
  const int* rows = ei;
  const int* cols = ei + E;

  float* fill = (float*)d_out;    // [N]
  float* ew = (float*)d_out + N;  // [E] edge_weights output slice

  // workspace carve-up (256B aligned)
  char* w = (char*)d_ws;
  size_t off_b = 0;
  auto alloc = [&](size_t bytes) -> void* {
    void* p = (void*)(w + off_b);
    off_b = (off_b + bytes + 255) & ~(size_t)255;
    return p;
  };
  const int Wn = (N + 1) / 2;  // packed words per copy (25000)
  __half* hn = (__half*)alloc((size_t)N * D * sizeof(__half));  // 12.8 MB
  unsigned* cntp = (unsigned*)alloc((size_t)8 * Wn * sizeof(unsigned));  // .8M
  int* base8 = (int*)alloc((size_t)8 * N * sizeof(int));        // 1.6 MB
  unsigned short* rank =
      (unsigned short*)alloc((size_t)E * sizeof(unsigned short));  // 1.2 MB
  int* off = (int*)alloc((size_t)(N + 1) * sizeof(int));
  int* bsum = (int*)alloc(256 * sizeof(int));
  unsigned* rec = (unsigned*)alloc((size_t)E * sizeof(unsigned));  // 2.4 MB
  int* perm = (int*)alloc((size_t)E * sizeof(int));                // 2.4 MB
  float* csr_w = (float*)alloc((size_t)E * sizeof(float));         // 2.4 MB
  unsigned short* src16 =
      (unsigned short*)alloc((size_t)E * sizeof(unsigned short));
  float* h0 = (float*)alloc((size_t)N * sizeof(float));
  float* f_a = (float*)alloc((size_t)N * sizeof(float));
  float* f_b = (float*)alloc((size_t)N * sizeof(float));
  float* rsd = (float*)alloc((size_t)N * sizeof(float));
  (void)ws_size;

  const int NCH = (N + 255) / 256;  // 196 <= 256 (scan capacity)
  const int nb_E = (E + 255) / 256;
  const int NTILES = (N + 15) / 16;           // 3125 16-row tiles
  const int FRONT_BLOCKS = (NTILES + 7) / 8;  // 391: 4 waves x 2 tiles
  const int WSTRIDE = FRONT_BLOCKS * 4;       // 1564

  // zero packed counters (800KB)
  const int n4 = (8 * Wn + 3) / 4;
  k_zero<<<(n4 + 255) / 256, 256, 0, stream>>>((uint4*)cntp, n4);
  // 2-tile pipelined GEMM + inits + packed copy-split histogram/rank
  k_front<<<FRONT_BLOCKS, 256, 0, stream>>>(x, W, bl, mask, cols, hn, cntp,
                                            rank, h0, f_a, N, E, FRONT_BLOCKS,
                                            WSTRIDE, NTILES, Wn);
  // exclusive scan of totals -> off; unpacked per-copy bases -> base8
  k_scan_a<<<NCH, 256, 0, stream>>>(cntp, bsum, N, Wn);
  k_scan_bc<<<NCH, 256, 0, stream>>>(cntp, bsum, off, base8, N, E, NCH, Wn);
  // atomic-free col-sorted records + inverse permutation
  k_build<<<nb_E, 256, 0, stream>>>(rows, cols, base8, rank, rec, perm, N, E);
  // cosine in sorted order -> csr_w + src16 (2 edges per lane-quad)
  const int Q = (E + 1) / 2;
  k_edge_cos<<<(Q * 4 + 255) / 256, 256, 0, stream>>>(hn, rec, csr_w, src16,
                                                      E, Q);
  // un-permute raw weights to ew (d_out) + segmented degree -> rsd
  k_unperm_rsd<<<nb_E, 256, 0, stream>>>(csr_w, perm, off, ew, rsd, N, E);
  // K=5 APPNP iterations (gather-reduce; iter 0 normalizes csr_w in place)
  const float* fi = f_a;
  float* fo = f_b;
  for (int it = 0; it < 5; ++it) {
    int mode = (it == 0 ? 1 : 0) | (it == 4 ? 2 : 0);
    k_prop<<<(N * 4 + 255) / 256, 256, 0, stream>>>(
        fi, fo, csr_w, src16, off, h0, rsd, alpha, bias, fill, N, mode);
    const float* tmp = fo;
    fo = (float*)fi;
    fi = tmp;
  }
}